// Round 8
// baseline (962.640 us; speedup 1.0000x reference)
//
#include <hip/hip_runtime.h>

typedef __bf16 bf16x8 __attribute__((ext_vector_type(8)));
typedef float  v16f   __attribute__((ext_vector_type(16)));
typedef unsigned short ushort_t;

#define HH 768
#define WW 768
#define CH 3
#define KS 24
#define HC 745
#define WC 745
#define NP 256
#define XH 384
#define XW 384

#define NBX 24            // ceil(745/32)
#define NBY 187           // ceil(745/4)
#define NBLK (NBX*NBY)    // 4488
#define BROWS 4
#define BCOLS 32
#define NSTEP 54          // K=1728 in 32-wide slices
#define NCAND 8

// async global->LDS DMA; LDS dest = wave-uniform base + lane*size (global addr is per-lane)
__device__ __forceinline__ void gload16(const ushort_t* g, ushort_t* l) {
    __builtin_amdgcn_global_load_lds(
        (const __attribute__((address_space(1))) unsigned int*)(const void*)g,
        (__attribute__((address_space(3))) unsigned int*)(void*)l, 16, 0, 0);
}
__device__ __forceinline__ void gload4(const ushort_t* g, ushort_t* l) {
    __builtin_amdgcn_global_load_lds(
        (const __attribute__((address_space(1))) unsigned int*)(const void*)g,
        (__attribute__((address_space(3))) unsigned int*)(void*)l, 4, 0, 0);
}
__device__ __forceinline__ ushort_t f2bf(float f) {
    union { __bf16 h; ushort_t u; } cv; cv.h = (__bf16)f; return cv.u;
}
__device__ __forceinline__ float bf2f(ushort_t u) {
    union { unsigned u; float f; } cv; cv.u = ((unsigned)u) << 16; return cv.f;
}

// -------------------- prep kernels --------------------

__global__ void k_colsum(const float* __restrict__ y, float* __restrict__ ksum,
                         float* __restrict__ ksum2) {
    int idx = blockIdx.x * 256 + threadIdx.x;
    if (idx >= HH * WW) return;
    float a = y[idx], b = y[idx + HH * WW], c = y[idx + 2 * HH * WW];
    ksum[idx]  = a + b + c;
    ksum2[idx] = a * a + b * b + c * c;
}

__global__ void k_hsum(const float* __restrict__ ksum, const float* __restrict__ ksum2,
                       float* __restrict__ h1, float* __restrict__ h2) {
    int idx = blockIdx.x * 256 + threadIdx.x;
    if (idx >= HH * WC) return;
    int h = idx / WC, w = idx % WC;
    const float* r  = ksum  + h * WW + w;
    const float* r2 = ksum2 + h * WW + w;
    float s = 0.f, s2 = 0.f;
    #pragma unroll
    for (int j = 0; j < KS; j++) { s += r[j]; s2 += r2[j]; }
    h1[idx] = s; h2[idx] = s2;
}

// bf16 maps are ONLY used for the approximate pre-screen; k_rescore recomputes exactly.
__global__ void k_vsum(const float* __restrict__ h1, const float* __restrict__ h2,
                       ushort_t* __restrict__ s1m, ushort_t* __restrict__ ivm) {
    int idx = blockIdx.x * 256 + threadIdx.x;
    if (idx >= HC * WC) return;
    int r = idx / WC, w = idx % WC;
    float s = 0.f, s2 = 0.f;
    #pragma unroll
    for (int i = 0; i < KS; i++) { s += h1[(r + i) * WC + w]; s2 += h2[(r + i) * WC + w]; }
    float d2 = s2 - s * s * (1.0f / 576.0f);
    s1m[idx] = f2bf(s);
    ivm[idx] = f2bf(rsqrtf(fmaxf(d2, 1e-20f)));
}

__global__ void k_meanx(const float* __restrict__ x, float* __restrict__ mx) {
    int p = blockIdx.x;
    int pr = p >> 4, pc = p & 15;
    float s = 0.f;
    for (int e = threadIdx.x; e < CH * KS * KS; e += 256) {
        int c = e / (KS * KS); int rem = e % (KS * KS);
        int i = rem / KS, j = rem % KS;
        s += x[(c * XH + pr * KS + i) * XW + pc * KS + j];
    }
    __shared__ float red[256];
    red[threadIdx.x] = s; __syncthreads();
    for (int st = 128; st > 0; st >>= 1) {
        if (threadIdx.x < st) red[threadIdx.x] += red[threadIdx.x + st];
        __syncthreads();
    }
    if (threadIdx.x == 0) mx[p] = red[0] * (1.0f / 1728.0f);
}

__global__ void k_bmat(const float* __restrict__ x, ushort_t* __restrict__ bm) {
    int p = blockIdx.x; int pr = p >> 4, pc = p & 15;
    for (int e = threadIdx.x; e < CH * KS * KS; e += 256) {
        int c = e / (KS * KS), rem = e % (KS * KS), i = rem / KS, j = rem % KS;
        bm[p * 1728 + e] = f2bf(x[(c * XH + pr * KS + i) * XW + pc * KS + j]);
    }
}

// 2 column-shifted bf16 copies: y2[S][c][r][t] = bf16(ydec[c][r][t+S]), S in {0,1}, 0-pad OOB.
__global__ void k_y2(const float* __restrict__ yd, ushort_t* __restrict__ y2) {
    int idx = blockIdx.x * 256 + threadIdx.x;
    if (idx >= 2 * 3 * HH * (WW / 8)) return;
    int t8 = idx % (WW / 8); int rem = idx / (WW / 8);
    int r = rem % HH; rem /= HH;
    int c = rem % 3; int S = rem / 3;
    const float* src = yd + (c * HH + r) * WW;
    union { ushort_t u[8]; uint4 v; } o;
    #pragma unroll
    for (int q = 0; q < 8; q++) {
        int t = t8 * 8 + q + S;
        o.u[q] = f2bf(t < WW ? src[t] : 0.f);
    }
    ((uint4*)(y2 + ((size_t)(S * 3 + c) * HH + r) * WW))[t8] = o.v;
}

// -------------------- main MFMA correlation kernel --------------------
// 256 thr (4 waves), grid (NBLK, 2): tile = 128 pos (4x32) x 128 patches; wave tile 64x64
// of mfma_f32_32x32x16_bf16. Slot-major LDS [k-octet-plane][row][8] (conflict-free, R6).
// DOUBLE-BUFFERED K-loop with raw s_barrier + explicit vmcnt(10): slice s+1's DMA stays
// in flight while slice s computes — no vmcnt(0) drain per slice (R7's serializer).

__global__ __launch_bounds__(256, 4) void k_corr(
    const ushort_t* __restrict__ y2, const ushort_t* __restrict__ bmat,
    const ushort_t* __restrict__ s1m, const ushort_t* __restrict__ ivm,
    const float* __restrict__ mx, ushort_t* __restrict__ ps16)
{
    __shared__ __align__(16) ushort_t Ab[2 * 4096];   // 2 x 8KB [oct][pos][8]
    __shared__ __align__(16) ushort_t Bb[2 * 4096];   // 2 x 8KB [oct][pat][8]
    float* red = (float*)Ab;                          // epilogue-only alias (post-sync)

    const int tid = threadIdx.x;
    const int wave = tid >> 6, lane = tid & 63;
    const int bx = blockIdx.x % NBX, by = blockIdx.x / NBX;
    const int r0 = by * BROWS, w0 = bx * BCOLS;
    const int zbase = blockIdx.y * 128;                  // patch half

    // ---- A staging constants: round (u,h2): dest byte = u*2048 + h2*1024 + 4*tid ----
    const int pos0 = tid >> 2, dword = tid & 3;
    int a_toff[2];
    #pragma unroll
    for (int h2 = 0; h2 < 2; h2++) {
        int pos = h2 * 64 + pos0;
        int prow = pos >> 5, pcol = pos & 31;
        int Sp = pcol & 1;                               // w0 even, octet col-offset even
        a_toff[h2] = Sp * (3 * HH * WW) + prow * WW + pcol - Sp + dword * 2;
    }
    // ---- B staging: round q: dest byte = q*4096 + wave*1024 + 16*lane ----
    const int b_toff = (zbase + (wave & 1) * 64 + lane) * 1728 + (wave >> 1) * 8;

    const int l31 = lane & 31, h = lane >> 5;
    const int wm = wave >> 1, wn = wave & 1;

    v16f acc[2][2];
    #pragma unroll
    for (int a = 0; a < 2; a++)
        #pragma unroll
        for (int b = 0; b < 2; b++)
            #pragma unroll
            for (int r = 0; r < 16; r++) acc[a][b][r] = 0.f;

    const ushort_t* abase = y2 + (size_t)r0 * WW + w0;   // octet cursor (c=0,i=0,jj=0)
    int jc = 0, ic = 0;                                  // uniform cursor (SALU)
    const ushort_t* bbase = bmat;                        // += 32 per staged slice

    auto stage = [&](int buf) {
        ushort_t* ad = Ab + buf * 4096 + wave * 128;
        #pragma unroll
        for (int u = 0; u < 4; u++) {
            gload4(abase + a_toff[0], ad + u * 1024);
            gload4(abase + a_toff[1], ad + u * 1024 + 512);
            abase += 8;
            if (++jc == 3) {
                jc = 0; abase += WW - 24;
                if (++ic == 24) { ic = 0; abase += (size_t)(HH - 24) * WW; }
            }
        }
        ushort_t* bd = Bb + buf * 4096 + wave * 512;
        gload16(bbase + b_toff,      bd);
        gload16(bbase + b_toff + 16, bd + 2048);
        bbase += 32;
    };

    stage(0);                                            // prologue: slice 0 -> buf 0

    #pragma unroll 1
    for (int s = 0; s < NSTEP; s++) {
        const int cur = s & 1;
        if (s + 1 < NSTEP) {
            stage(cur ^ 1);                              // 10 DMAs for slice s+1 in flight
            asm volatile("s_waitcnt vmcnt(10)" ::: "memory");  // slice-s DMAs (older) done
        } else {
            asm volatile("s_waitcnt vmcnt(0)" ::: "memory");
        }
        asm volatile("s_barrier" ::: "memory");          // all waves: buf[cur] ready

        const ushort_t* Ac = Ab + cur * 4096;
        const ushort_t* Bc = Bb + cur * 4096;
        bf16x8 af[2][2], bfr[2][2];
        #pragma unroll
        for (int mt = 0; mt < 2; mt++)
            #pragma unroll
            for (int ks = 0; ks < 2; ks++)
                af[mt][ks] = *(const bf16x8*)(Ac + (ks * 2 + h) * 1024 + (wm * 64 + mt * 32 + l31) * 8);
        #pragma unroll
        for (int nt = 0; nt < 2; nt++)
            #pragma unroll
            for (int ks = 0; ks < 2; ks++)
                bfr[nt][ks] = *(const bf16x8*)(Bc + (ks * 2 + h) * 1024 + (wn * 64 + nt * 32 + l31) * 8);
        #pragma unroll
        for (int ks = 0; ks < 2; ks++)
            #pragma unroll
            for (int mt = 0; mt < 2; mt++)
                #pragma unroll
                for (int nt = 0; nt < 2; nt++)
                    acc[mt][nt] = __builtin_amdgcn_mfma_f32_32x32x16_bf16(
                        af[mt][ks], bfr[nt][ks], acc[mt][nt], 0, 0, 0);

        asm volatile("s_waitcnt lgkmcnt(0)" ::: "memory");  // own reads of buf[cur] done
        asm volatile("s_barrier" ::: "memory");             // all readers done before overwrite
    }

    // epilogue: approx score + per-(patch, block) max
    float mx0 = mx[zbase + wn * 64 + l31];
    float mx1 = mx[zbase + wn * 64 + 32 + l31];
    float best0 = -1e30f, best1 = -1e30f;
    #pragma unroll
    for (int mt = 0; mt < 2; mt++) {
        #pragma unroll
        for (int r = 0; r < 16; r++) {
            int row32 = (r & 3) + 8 * (r >> 2) + 4 * h;   // 32x32 C/D row (m74/m101)
            int posid = wm * 64 + mt * 32 + row32;
            int rg = r0 + (posid >> 5), wg = w0 + (posid & 31);
            bool valid = (rg < HC) && (wg < WC);
            int pos = rg * WC + wg;
            float S1 = valid ? bf2f(s1m[pos]) : 0.f;
            float iv = valid ? bf2f(ivm[pos]) : 0.f;
            float sc0 = valid ? (acc[mt][0][r] - mx0 * S1) * iv : -1e30f;
            float sc1 = valid ? (acc[mt][1][r] - mx1 * S1) * iv : -1e30f;
            best0 = fmaxf(best0, sc0);
            best1 = fmaxf(best1, sc1);
        }
    }
    best0 = fmaxf(best0, __shfl_xor(best0, 32));         // reduce over h
    best1 = fmaxf(best1, __shfl_xor(best1, 32));
    __syncthreads();                                     // full drain; Ab reused as red
    if (h == 0) {
        red[(wn * 64 + l31) * 2 + wm]      = best0;
        red[(wn * 64 + 32 + l31) * 2 + wm] = best1;
    }
    __syncthreads();
    if (tid < 128)
        ps16[blockIdx.x * NP + zbase + tid] = f2bf(fmaxf(red[tid * 2], red[tid * 2 + 1]));
}

// -------------------- per-patch top-8 blocks --------------------

__global__ void k_select(const ushort_t* __restrict__ ps16, int* __restrict__ cand) {
    int p = blockIdx.x, tid = threadIdx.x;
    __shared__ float ls[NBLK];
    __shared__ float rs[256];
    __shared__ int   ri[256];
    for (int e = tid; e < NBLK; e += 256) ls[e] = bf2f(ps16[e * NP + p]);
    __syncthreads();
    for (int round = 0; round < NCAND; round++) {
        float bs = -1e38f; int bi = 0;
        for (int e = tid; e < NBLK; e += 256) if (ls[e] > bs) { bs = ls[e]; bi = e; }
        rs[tid] = bs; ri[tid] = bi; __syncthreads();
        for (int st = 128; st > 0; st >>= 1) {
            if (tid < st && rs[tid + st] > rs[tid]) { rs[tid] = rs[tid + st]; ri[tid] = ri[tid + st]; }
            __syncthreads();
        }
        int win = ri[0];
        if (tid == 0) cand[p * NCAND + round] = win;
        if (tid == (win & 255)) ls[win] = -1e38f;
        __syncthreads();
    }
}

// -------------------- exact fp32 rescore (recomputes window sums) + gather --------------------

__global__ void k_rescore(const int* __restrict__ cand, const float* __restrict__ xdec,
                          const float* __restrict__ ydec, const float* __restrict__ mx,
                          const float* __restrict__ yfull, float* __restrict__ out) {
    int p = blockIdx.x, tid = threadIdx.x;
    int pr = p >> 4, pc = p & 15;
    float mxp = mx[p];
    float best = -1e30f; int bpos = 0x7FFFFFFF;
    #pragma unroll 1
    for (int cdp = 0; cdp < 4; cdp++) {
        int cd = cdp * 2 + (tid >> 7);
        int blk = cand[p * NCAND + cd];
        int r0 = (blk / NBX) * BROWS, w0 = (blk % NBX) * BCOLS;
        int pi = tid & 127;
        int rg = r0 + (pi >> 5), wg = w0 + (pi & 31);
        if (rg < HC && wg < WC) {
            float sxy = 0.f, sy = 0.f, sy2 = 0.f;
            for (int c = 0; c < CH; c++) {
                #pragma unroll 1
                for (int i = 0; i < KS; i++) {
                    const float* yr = ydec + (c * HH + rg + i) * WW + wg;
                    const float* xr = xdec + (c * XH + pr * KS + i) * XW + pc * KS;
                    #pragma unroll
                    for (int j = 0; j < KS; j++) {
                        float yv = yr[j];
                        sxy = fmaf(yv, xr[j], sxy);
                        sy += yv;
                        sy2 = fmaf(yv, yv, sy2);
                    }
                }
            }
            float d2 = sy2 - sy * sy * (1.0f / 576.0f);
            int pos = rg * WC + wg;
            float sc = (sxy - mxp * sy) * rsqrtf(fmaxf(d2, 1e-20f));
            if (sc > best || (sc == best && pos < bpos)) { best = sc; bpos = pos; }
        }
    }
    __shared__ float rs[256];
    __shared__ int   ri[256];
    rs[tid] = best; ri[tid] = bpos; __syncthreads();
    for (int st = 128; st > 0; st >>= 1) {
        if (tid < st) {
            if (rs[tid + st] > rs[tid] || (rs[tid + st] == rs[tid] && ri[tid + st] < ri[tid])) {
                rs[tid] = rs[tid + st]; ri[tid] = ri[tid + st];
            }
        }
        __syncthreads();
    }
    int bestpos = ri[0];
    int row = bestpos / WC, col = bestpos % WC;
    for (int e = tid; e < CH * KS * KS; e += 256) {
        int c = e / (KS * KS), rem = e % (KS * KS), i = rem / KS, j = rem % KS;
        out[p * CH * KS * KS + e] = yfull[(c * HH + row + i) * WW + col + j];
    }
}

// -------------------- launch --------------------
// ws high-water: writes to 3,122,464 floats (11.9 MB); transient OOB *reads* reach
// ~3,123,700 floats (12.49 MB) — safely under the >=13.7 MB proven by R1-R3.

extern "C" void kernel_launch(void* const* d_in, const int* in_sizes, int n_in,
                              void* d_out, int out_size, void* d_ws, size_t ws_size,
                              hipStream_t stream) {
    const float* xdec = (const float*)d_in[0];   // (1,3,384,384)
    const float* ydec = (const float*)d_in[1];   // (1,3,768,768)
    const float* y    = (const float*)d_in[2];   // (1,3,768,768)
    float* out = (float*)d_out;                  // (256,3,24,24)

    float* ws = (float*)d_ws;
    ushort_t* s1m16 = (ushort_t*)(ws + 0);         // 555025 u16 (pad to 277520 floats)
    ushort_t* ivm16 = (ushort_t*)(ws + 277520);    // 555025 u16
    float*    mx    = ws + 555040;                 // 256
    ushort_t* Bmat  = (ushort_t*)(ws + 555296);    // 442368 u16 (16B-aligned)
    int*      cand  = (int*)(ws + 776480);         // 2048
    ushort_t* ps16  = (ushort_t*)(ws + 778528);    // 1,148,928 u16 [blk][pat]
    ushort_t* y2    = (ushort_t*)(ws + 1352992);   // 3,538,944 u16 (16B-aligned)
    // box-sum temps alias ps16+y2 region (dead before k_y2/k_corr):
    float* ksum  = ws + 778528;                    // 589824
    float* ksum2 = ws + 1368352;                   // 589824
    float* h1    = ws + 1958176;                   // 572160
    float* h2    = ws + 2530336;                   // 572160 (end 3,102,496)

    k_colsum<<<(HH * WW + 255) / 256, 256, 0, stream>>>(ydec, ksum, ksum2);
    k_hsum<<<(HH * WC + 255) / 256, 256, 0, stream>>>(ksum, ksum2, h1, h2);
    k_vsum<<<(HC * WC + 255) / 256, 256, 0, stream>>>(h1, h2, s1m16, ivm16);
    k_meanx<<<NP, 256, 0, stream>>>(xdec, mx);
    k_bmat<<<NP, 256, 0, stream>>>(xdec, Bmat);
    k_y2<<<(2 * 3 * HH * (WW / 8) + 255) / 256, 256, 0, stream>>>(ydec, y2);

    dim3 grid(NBLK, 2);
    k_corr<<<grid, 256, 0, stream>>>(y2, Bmat, s1m16, ivm16, mx, ps16);
    k_select<<<NP, 256, 0, stream>>>(ps16, cand);
    k_rescore<<<NP, 256, 0, stream>>>(cand, xdec, ydec, mx, y, out);
}

// Round 9
// 879.120 us; speedup vs baseline: 1.0950x; 1.0950x over previous
//
#include <hip/hip_runtime.h>

typedef float v16f __attribute__((ext_vector_type(16)));
typedef unsigned short ushort_t;
typedef unsigned char uchar_t;
typedef long long ll_t;

#define HH 768
#define WW 768
#define CH 3
#define KS 24
#define HC 745
#define WC 745
#define NP 256
#define XH 384
#define XW 384

#define NBX 24            // ceil(745/32)
#define NBY 187           // ceil(745/4)
#define NBLK (NBX*NBY)    // 4488
#define BROWS 4
#define BCOLS 32
#define NSTEP 27          // K=1728 in 64-wide slices (8 octets each)
#define NCAND 8

// async global->LDS DMA; LDS dest = wave-uniform base + lane*size (global addr per-lane)
__device__ __forceinline__ void gload16(const uchar_t* g, uchar_t* l) {
    __builtin_amdgcn_global_load_lds(
        (const __attribute__((address_space(1))) unsigned int*)(const void*)g,
        (__attribute__((address_space(3))) unsigned int*)(void*)l, 16, 0, 0);
}
__device__ __forceinline__ void gload4(const uchar_t* g, uchar_t* l) {
    __builtin_amdgcn_global_load_lds(
        (const __attribute__((address_space(1))) unsigned int*)(const void*)g,
        (__attribute__((address_space(3))) unsigned int*)(void*)l, 4, 0, 0);
}
__device__ __forceinline__ ushort_t f2bf(float f) {
    union { __bf16 h; ushort_t u; } cv; cv.h = (__bf16)f; return cv.u;
}
__device__ __forceinline__ float bf2f(ushort_t u) {
    union { unsigned u; float f; } cv; cv.u = ((unsigned)u) << 16; return cv.f;
}
// fp32 -> OCP e4m3fn (RNE for normals; grid-round for subnormals). Screen-only precision.
__device__ __forceinline__ uchar_t f2e4m3(float f) {
    unsigned u = __float_as_uint(f);
    unsigned s = (u >> 24) & 0x80;
    float a = fabsf(f);
    if (a < 0.0078125f) {                       // < 2^-7 -> subnormal grid 2^-9
        int q = (int)(a * 512.0f + 0.5f);
        return (uchar_t)(s | (unsigned)q);
    }
    int e = (int)((u >> 23) & 0xFF);
    unsigned m = (u >> 20) & 7;
    unsigned rest = u & 0xFFFFF;
    if (rest > 0x80000 || (rest == 0x80000 && (m & 1))) { m++; if (m == 8) { m = 0; e++; } }
    int e8 = e - 120;                           // -127 + 7
    if (e8 <= 0) { int q = (int)(a * 512.0f + 0.5f); if (q > 7) q = 7; return (uchar_t)(s | q); }
    if (e8 > 15) return (uchar_t)(s | 0x7E);    // clamp to 448 (inputs never reach)
    return (uchar_t)(s | ((unsigned)e8 << 3) | m);
}

// -------------------- prep kernels --------------------

__global__ void k_colsum(const float* __restrict__ y, float* __restrict__ ksum,
                         float* __restrict__ ksum2) {
    int idx = blockIdx.x * 256 + threadIdx.x;
    if (idx >= HH * WW) return;
    float a = y[idx], b = y[idx + HH * WW], c = y[idx + 2 * HH * WW];
    ksum[idx]  = a + b + c;
    ksum2[idx] = a * a + b * b + c * c;
}

__global__ void k_hsum(const float* __restrict__ ksum, const float* __restrict__ ksum2,
                       float* __restrict__ h1, float* __restrict__ h2) {
    int idx = blockIdx.x * 256 + threadIdx.x;
    if (idx >= HH * WC) return;
    int h = idx / WC, w = idx % WC;
    const float* r  = ksum  + h * WW + w;
    const float* r2 = ksum2 + h * WW + w;
    float s = 0.f, s2 = 0.f;
    #pragma unroll
    for (int j = 0; j < KS; j++) { s += r[j]; s2 += r2[j]; }
    h1[idx] = s; h2[idx] = s2;
}

// bf16 maps are ONLY used for the approximate pre-screen; k_rescore recomputes exactly.
__global__ void k_vsum(const float* __restrict__ h1, const float* __restrict__ h2,
                       ushort_t* __restrict__ s1m, ushort_t* __restrict__ ivm) {
    int idx = blockIdx.x * 256 + threadIdx.x;
    if (idx >= HC * WC) return;
    int r = idx / WC, w = idx % WC;
    float s = 0.f, s2 = 0.f;
    #pragma unroll
    for (int i = 0; i < KS; i++) { s += h1[(r + i) * WC + w]; s2 += h2[(r + i) * WC + w]; }
    float d2 = s2 - s * s * (1.0f / 576.0f);
    s1m[idx] = f2bf(s);
    ivm[idx] = f2bf(rsqrtf(fmaxf(d2, 1e-20f)));
}

__global__ void k_meanx(const float* __restrict__ x, float* __restrict__ mx) {
    int p = blockIdx.x;
    int pr = p >> 4, pc = p & 15;
    float s = 0.f;
    for (int e = threadIdx.x; e < CH * KS * KS; e += 256) {
        int c = e / (KS * KS); int rem = e % (KS * KS);
        int i = rem / KS, j = rem % KS;
        s += x[(c * XH + pr * KS + i) * XW + pc * KS + j];
    }
    __shared__ float red[256];
    red[threadIdx.x] = s; __syncthreads();
    for (int st = 128; st > 0; st >>= 1) {
        if (threadIdx.x < st) red[threadIdx.x] += red[threadIdx.x + st];
        __syncthreads();
    }
    if (threadIdx.x == 0) mx[p] = red[0] * (1.0f / 1728.0f);
}

// fp8 patch matrix, k = (c*24+i)*24+j, patch-major rows of 1728 B
__global__ void k_bmat8(const float* __restrict__ x, uchar_t* __restrict__ bm) {
    int p = blockIdx.x; int pr = p >> 4, pc = p & 15;
    for (int e = threadIdx.x; e < CH * KS * KS; e += 256) {
        int c = e / (KS * KS), rem = e % (KS * KS), i = rem / KS, j = rem % KS;
        bm[p * 1728 + e] = f2e4m3(x[(c * XH + pr * KS + i) * XW + pc * KS + j]);
    }
}

// 4 column-shifted fp8 copies: y4[S][c][r][t] = fp8(ydec[c][r][t+S]), S in 0..3, 0-pad OOB.
__global__ void k_y4(const float* __restrict__ yd, uchar_t* __restrict__ y4) {
    int idx = blockIdx.x * 256 + threadIdx.x;       // one 4-chunk each
    if (idx >= 4 * 3 * HH * (WW / 4)) return;
    int q = idx % (WW / 4); int rem = idx / (WW / 4);
    int r = rem % HH; rem /= HH;
    int c = rem % 3; int S = rem / 3;
    const float* src = yd + (c * HH + r) * WW;
    union { uchar_t u[4]; unsigned v; } o;
    #pragma unroll
    for (int qq = 0; qq < 4; qq++) {
        int t = q * 4 + qq + S;
        o.u[qq] = f2e4m3(t < WW ? src[t] : 0.f);
    }
    ((unsigned*)(y4 + ((size_t)(S * 3 + c) * HH + r) * WW))[q] = o.v;
}

// -------------------- main MFMA correlation kernel (fp8) --------------------
// 256 thr (4 waves), grid (NBLK, 2): tile = 128 pos (4x32) x 128 patches; wave tile 64x64
// of mfma_f32_32x32x16_fp8_fp8 (frags 8 B/lane -> ds_read_b64; half the LDS traffic of
// bf16, which was the saturated pipe in R6-R8). K=64 slices (27 iters) amortize barriers.
// A LDS: [oct 0..7][pos 0..127][8B]; B LDS: [octpair 0..3][pat 0..127][16B].

__global__ __launch_bounds__(256, 4) void k_corr(
    const uchar_t* __restrict__ y4, const uchar_t* __restrict__ bmat,
    const ushort_t* __restrict__ s1m, const ushort_t* __restrict__ ivm,
    const float* __restrict__ mx, ushort_t* __restrict__ ps16)
{
    __shared__ __align__(16) uchar_t Ab[8 * 1024];   // 8KB
    __shared__ __align__(16) uchar_t Bb[4 * 2048];   // 8KB
    float* red = (float*)Ab;                          // epilogue-only alias (post-sync)

    const int tid = threadIdx.x;
    const int wave = tid >> 6, lane = tid & 63;
    const int bx = blockIdx.x % NBX, by = blockIdx.x / NBX;
    const int r0 = by * BROWS, w0 = bx * BCOLS;
    const int zbase = blockIdx.y * 128;              // patch half

    // ---- A staging: round u (octet u of slice): dest byte = u*1024 + 4*tid ----
    // pos = tid>>1, half = tid&1; 4 fp8 elems at col w0+pcol+j0+half*4 from parity copy.
    const int apos = tid >> 1, ahalf = tid & 1;
    const int aprow = apos >> 5, apcol = apos & 31;
    const int Sp = apcol & 3;                        // col mod 4 -> shifted copy (4B align)
    const int a_toff = Sp * (3 * HH * WW) + aprow * WW + (apcol - Sp) + ahalf * 4;
    uchar_t* adst = Ab + wave * 256;                 // + u*1024 (wave-uniform; +lane*4 by HW)

    // ---- B staging: round q (octpairs 2q,2q+1): dest byte = q*4096 + 16*tid ----
    // thread covers pat = tid&127, octpair = (tid>>7) + 2q; 16 contiguous k in bmat.
    const int b_toff = (zbase + (tid & 127)) * 1728 + (tid >> 7) * 16;
    uchar_t* bdst = Bb + (tid >> 7) * 2048 + 0;      // base handled wave-uniform below
    // NOTE: dest must be wave-uniform + lane*16: byte 16*tid = wave*1024 + lane*16 ✓
    uchar_t* bdstw = Bb + wave * 1024;               // + q*4096

    const int l31 = lane & 31, h = lane >> 5;
    const int wm = wave >> 1, wn = wave & 1;

    v16f acc[2][2];
    #pragma unroll
    for (int a = 0; a < 2; a++)
        #pragma unroll
        for (int b = 0; b < 2; b++)
            #pragma unroll
            for (int r = 0; r < 16; r++) acc[a][b][r] = 0.f;

    const uchar_t* abase = y4 + (size_t)r0 * WW + w0;    // octet cursor (c=0,i=0,j=0)
    int jc = 0, ic = 0;                                  // uniform cursor (SALU)
    const uchar_t* bbase = bmat;                         // += 64 per slice

    #pragma unroll 1
    for (int s = 0; s < NSTEP; s++) {
        __syncthreads();                                 // old tile fully consumed
        #pragma unroll
        for (int u = 0; u < 8; u++) {                    // A octets (8 x 1KB)
            gload4(abase + a_toff, adst + u * 1024);
            abase += 8;
            if (++jc == 3) {
                jc = 0; abase += WW - 24;
                if (++ic == 24) { ic = 0; abase += (size_t)(HH - 24) * WW; }
            }
        }
        gload16(bbase + b_toff,      bdstw);             // B octpairs 0,1 (4KB)
        gload16(bbase + b_toff + 32, bdstw + 4096);      // B octpairs 2,3
        bbase += 64;
        __syncthreads();                                 // staging landed

        ll_t af[2][4], bf[2][4];
        #pragma unroll
        for (int mt = 0; mt < 2; mt++)
            #pragma unroll
            for (int ks = 0; ks < 4; ks++)
                af[mt][ks] = *(const ll_t*)(Ab + (ks * 2 + h) * 1024 + (wm * 64 + mt * 32 + l31) * 8);
        #pragma unroll
        for (int nt = 0; nt < 2; nt++)
            #pragma unroll
            for (int ks = 0; ks < 4; ks++)
                bf[nt][ks] = *(const ll_t*)(Bb + ks * 2048 + (wn * 64 + nt * 32 + l31) * 16 + h * 8);
        #pragma unroll
        for (int ks = 0; ks < 4; ks++)
            #pragma unroll
            for (int mt = 0; mt < 2; mt++)
                #pragma unroll
                for (int nt = 0; nt < 2; nt++)
                    acc[mt][nt] = __builtin_amdgcn_mfma_f32_32x32x16_fp8_fp8(
                        af[mt][ks], bf[nt][ks], acc[mt][nt], 0, 0, 0);
    }

    // epilogue: approx score + per-(patch, block) max
    float mx0 = mx[zbase + wn * 64 + l31];
    float mx1 = mx[zbase + wn * 64 + 32 + l31];
    float best0 = -1e30f, best1 = -1e30f;
    #pragma unroll
    for (int mt = 0; mt < 2; mt++) {
        #pragma unroll
        for (int r = 0; r < 16; r++) {
            int row32 = (r & 3) + 8 * (r >> 2) + 4 * h;   // 32x32 C/D row (m74/m101)
            int posid = wm * 64 + mt * 32 + row32;
            int rg = r0 + (posid >> 5), wg = w0 + (posid & 31);
            bool valid = (rg < HC) && (wg < WC);
            int pos = rg * WC + wg;
            float S1 = valid ? bf2f(s1m[pos]) : 0.f;
            float iv = valid ? bf2f(ivm[pos]) : 0.f;
            float sc0 = valid ? (acc[mt][0][r] - mx0 * S1) * iv : -1e30f;
            float sc1 = valid ? (acc[mt][1][r] - mx1 * S1) * iv : -1e30f;
            best0 = fmaxf(best0, sc0);
            best1 = fmaxf(best1, sc1);
        }
    }
    best0 = fmaxf(best0, __shfl_xor(best0, 32));         // reduce over h
    best1 = fmaxf(best1, __shfl_xor(best1, 32));
    __syncthreads();                                     // full drain; Ab reused as red
    if (h == 0) {
        red[(wn * 64 + l31) * 2 + wm]      = best0;
        red[(wn * 64 + 32 + l31) * 2 + wm] = best1;
    }
    __syncthreads();
    if (tid < 128)
        ps16[blockIdx.x * NP + zbase + tid] = f2bf(fmaxf(red[tid * 2], red[tid * 2 + 1]));
}

// -------------------- per-patch top-8 blocks --------------------

__global__ void k_select(const ushort_t* __restrict__ ps16, int* __restrict__ cand) {
    int p = blockIdx.x, tid = threadIdx.x;
    __shared__ float ls[NBLK];
    __shared__ float rs[256];
    __shared__ int   ri[256];
    for (int e = tid; e < NBLK; e += 256) ls[e] = bf2f(ps16[e * NP + p]);
    __syncthreads();
    for (int round = 0; round < NCAND; round++) {
        float bs = -1e38f; int bi = 0;
        for (int e = tid; e < NBLK; e += 256) if (ls[e] > bs) { bs = ls[e]; bi = e; }
        rs[tid] = bs; ri[tid] = bi; __syncthreads();
        for (int st = 128; st > 0; st >>= 1) {
            if (tid < st && rs[tid + st] > rs[tid]) { rs[tid] = rs[tid + st]; ri[tid] = ri[tid + st]; }
            __syncthreads();
        }
        int win = ri[0];
        if (tid == 0) cand[p * NCAND + round] = win;
        if (tid == (win & 255)) ls[win] = -1e38f;
        __syncthreads();
    }
}

// -------------------- exact fp32 rescore (recomputes window sums) + gather --------------------

__global__ void k_rescore(const int* __restrict__ cand, const float* __restrict__ xdec,
                          const float* __restrict__ ydec, const float* __restrict__ mx,
                          const float* __restrict__ yfull, float* __restrict__ out) {
    int p = blockIdx.x, tid = threadIdx.x;
    int pr = p >> 4, pc = p & 15;
    float mxp = mx[p];
    float best = -1e30f; int bpos = 0x7FFFFFFF;
    #pragma unroll 1
    for (int cdp = 0; cdp < 4; cdp++) {
        int cd = cdp * 2 + (tid >> 7);
        int blk = cand[p * NCAND + cd];
        int r0 = (blk / NBX) * BROWS, w0 = (blk % NBX) * BCOLS;
        int pi = tid & 127;
        int rg = r0 + (pi >> 5), wg = w0 + (pi & 31);
        if (rg < HC && wg < WC) {
            float sxy = 0.f, sy = 0.f, sy2 = 0.f;
            for (int c = 0; c < CH; c++) {
                #pragma unroll 1
                for (int i = 0; i < KS; i++) {
                    const float* yr = ydec + (c * HH + rg + i) * WW + wg;
                    const float* xr = xdec + (c * XH + pr * KS + i) * XW + pc * KS;
                    #pragma unroll
                    for (int j = 0; j < KS; j++) {
                        float yv = yr[j];
                        sxy = fmaf(yv, xr[j], sxy);
                        sy += yv;
                        sy2 = fmaf(yv, yv, sy2);
                    }
                }
            }
            float d2 = sy2 - sy * sy * (1.0f / 576.0f);
            int pos = rg * WC + wg;
            float sc = (sxy - mxp * sy) * rsqrtf(fmaxf(d2, 1e-20f));
            if (sc > best || (sc == best && pos < bpos)) { best = sc; bpos = pos; }
        }
    }
    __shared__ float rs[256];
    __shared__ int   ri[256];
    rs[tid] = best; ri[tid] = bpos; __syncthreads();
    for (int st = 128; st > 0; st >>= 1) {
        if (tid < st) {
            if (rs[tid + st] > rs[tid] || (rs[tid + st] == rs[tid] && ri[tid + st] < ri[tid])) {
                rs[tid] = rs[tid + st]; ri[tid] = ri[tid + st];
            }
        }
        __syncthreads();
    }
    int bestpos = ri[0];
    int row = bestpos / WC, col = bestpos % WC;
    for (int e = tid; e < CH * KS * KS; e += 256) {
        int c = e / (KS * KS), rem = e % (KS * KS), i = rem / KS, j = rem % KS;
        out[p * CH * KS * KS + e] = yfull[(c * HH + row + i) * WW + col + j];
    }
}

// -------------------- launch --------------------
// ws footprint: 3,011,872 floats = 11.5 MB writes (OOB A-reads for masked-invalid
// positions stay < 12 MB) — under the >=13.7 MB proven by R1-R3.

extern "C" void kernel_launch(void* const* d_in, const int* in_sizes, int n_in,
                              void* d_out, int out_size, void* d_ws, size_t ws_size,
                              hipStream_t stream) {
    const float* xdec = (const float*)d_in[0];   // (1,3,384,384)
    const float* ydec = (const float*)d_in[1];   // (1,3,768,768)
    const float* y    = (const float*)d_in[2];   // (1,3,768,768)
    float* out = (float*)d_out;                  // (256,3,24,24)

    float* ws = (float*)d_ws;
    ushort_t* s1m16 = (ushort_t*)(ws + 0);         // 555025 u16
    ushort_t* ivm16 = (ushort_t*)(ws + 277520);    // 555025 u16
    float*    mx    = ws + 555040;                 // 256
    uchar_t*  Bmat8 = (uchar_t*)(ws + 555296);     // 442368 B (16B-aligned)
    int*      cand  = (int*)(ws + 665888);         // 2048
    ushort_t* ps16  = (ushort_t*)(ws + 667936);    // 1,148,928 u16 [blk][pat]
    uchar_t*  y4    = (uchar_t*)(ws + 1242400);    // 7,077,888 B (16B-aligned)
    // box-sum temps alias ps16+y4 region (dead before k_y4/k_corr):
    float* ksum  = ws + 667936;                    // 589824
    float* ksum2 = ws + 1257760;                   // 589824
    float* h1    = ws + 1847584;                   // 572160
    float* h2    = ws + 2419744;                   // 572160 (end 2,991,904 < 3,011,872)

    k_colsum<<<(HH * WW + 255) / 256, 256, 0, stream>>>(ydec, ksum, ksum2);
    k_hsum<<<(HH * WC + 255) / 256, 256, 0, stream>>>(ksum, ksum2, h1, h2);
    k_vsum<<<(HC * WC + 255) / 256, 256, 0, stream>>>(h1, h2, s1m16, ivm16);
    k_meanx<<<NP, 256, 0, stream>>>(xdec, mx);
    k_bmat8<<<NP, 256, 0, stream>>>(xdec, Bmat8);
    k_y4<<<(4 * 3 * HH * (WW / 4) + 255) / 256, 256, 0, stream>>>(ydec, y4);

    dim3 grid(NBLK, 2);
    k_corr<<<grid, 256, 0, stream>>>(y4, Bmat8, s1m16, ivm16, mx, ps16);
    k_select<<<NP, 256, 0, stream>>>(ps16, cand);
    k_rescore<<<NP, 256, 0, stream>>>(cand, xdec, ydec, mx, y, out);
}

// Round 10
// 838.011 us; speedup vs baseline: 1.1487x; 1.0491x over previous
//
#include <hip/hip_runtime.h>

typedef float v16f __attribute__((ext_vector_type(16)));
typedef unsigned short ushort_t;
typedef unsigned char uchar_t;
typedef long long ll_t;

#define HH 768
#define WW 768
#define CH 3
#define KS 24
#define HC 745
#define WC 745
#define NP 256
#define XH 384
#define XW 384

#define NBX 24            // ceil(745/32)
#define NBY 187           // ceil(745/4)
#define NBLK (NBX*NBY)    // 4488
#define BROWS 4
#define BCOLS 32
#define NSTEP 27          // K=1728 in 64-wide slices (8 octets each)
#define NCAND 8
#define NGRID (8*1152)    // XCD-banded launch (some idle)

// async global->LDS DMA; LDS dest = wave-uniform base + lane*size (global addr per-lane)
__device__ __forceinline__ void gload16(const uchar_t* g, uchar_t* l) {
    __builtin_amdgcn_global_load_lds(
        (const __attribute__((address_space(1))) unsigned int*)(const void*)g,
        (__attribute__((address_space(3))) unsigned int*)(void*)l, 16, 0, 0);
}
__device__ __forceinline__ void gload4(const uchar_t* g, uchar_t* l) {
    __builtin_amdgcn_global_load_lds(
        (const __attribute__((address_space(1))) unsigned int*)(const void*)g,
        (__attribute__((address_space(3))) unsigned int*)(void*)l, 4, 0, 0);
}
__device__ __forceinline__ ushort_t f2bf(float f) {
    union { __bf16 h; ushort_t u; } cv; cv.h = (__bf16)f; return cv.u;
}
__device__ __forceinline__ float bf2f(ushort_t u) {
    union { unsigned u; float f; } cv; cv.u = ((unsigned)u) << 16; return cv.f;
}
// fp32 -> OCP e4m3fn (RNE for normals; grid-round for subnormals). Screen-only precision.
__device__ __forceinline__ uchar_t f2e4m3(float f) {
    unsigned u = __float_as_uint(f);
    unsigned s = (u >> 24) & 0x80;
    float a = fabsf(f);
    if (a < 0.0078125f) {
        int q = (int)(a * 512.0f + 0.5f);
        return (uchar_t)(s | (unsigned)q);
    }
    int e = (int)((u >> 23) & 0xFF);
    unsigned m = (u >> 20) & 7;
    unsigned rest = u & 0xFFFFF;
    if (rest > 0x80000 || (rest == 0x80000 && (m & 1))) { m++; if (m == 8) { m = 0; e++; } }
    int e8 = e - 120;
    if (e8 <= 0) { int q = (int)(a * 512.0f + 0.5f); if (q > 7) q = 7; return (uchar_t)(s | q); }
    if (e8 > 15) return (uchar_t)(s | 0x7E);
    return (uchar_t)(s | ((unsigned)e8 << 3) | m);
}

// -------------------- prep kernels --------------------

__global__ void k_colsum(const float* __restrict__ y, float* __restrict__ ksum,
                         float* __restrict__ ksum2) {
    int idx = blockIdx.x * 256 + threadIdx.x;
    if (idx >= HH * WW) return;
    float a = y[idx], b = y[idx + HH * WW], c = y[idx + 2 * HH * WW];
    ksum[idx]  = a + b + c;
    ksum2[idx] = a * a + b * b + c * c;
}

__global__ void k_hsum(const float* __restrict__ ksum, const float* __restrict__ ksum2,
                       float* __restrict__ h1, float* __restrict__ h2) {
    int idx = blockIdx.x * 256 + threadIdx.x;
    if (idx >= HH * WC) return;
    int h = idx / WC, w = idx % WC;
    const float* r  = ksum  + h * WW + w;
    const float* r2 = ksum2 + h * WW + w;
    float s = 0.f, s2 = 0.f;
    #pragma unroll
    for (int j = 0; j < KS; j++) { s += r[j]; s2 += r2[j]; }
    h1[idx] = s; h2[idx] = s2;
}

// bf16 maps are ONLY used for the approximate pre-screen; k_rescore recomputes exactly.
__global__ void k_vsum(const float* __restrict__ h1, const float* __restrict__ h2,
                       ushort_t* __restrict__ s1m, ushort_t* __restrict__ ivm) {
    int idx = blockIdx.x * 256 + threadIdx.x;
    if (idx >= HC * WC) return;
    int r = idx / WC, w = idx % WC;
    float s = 0.f, s2 = 0.f;
    #pragma unroll
    for (int i = 0; i < KS; i++) { s += h1[(r + i) * WC + w]; s2 += h2[(r + i) * WC + w]; }
    float d2 = s2 - s * s * (1.0f / 576.0f);
    s1m[idx] = f2bf(s);
    ivm[idx] = f2bf(rsqrtf(fmaxf(d2, 1e-20f)));
}

__global__ void k_meanx(const float* __restrict__ x, float* __restrict__ mx) {
    int p = blockIdx.x;
    int pr = p >> 4, pc = p & 15;
    float s = 0.f;
    for (int e = threadIdx.x; e < CH * KS * KS; e += 256) {
        int c = e / (KS * KS); int rem = e % (KS * KS);
        int i = rem / KS, j = rem % KS;
        s += x[(c * XH + pr * KS + i) * XW + pc * KS + j];
    }
    __shared__ float red[256];
    red[threadIdx.x] = s; __syncthreads();
    for (int st = 128; st > 0; st >>= 1) {
        if (threadIdx.x < st) red[threadIdx.x] += red[threadIdx.x + st];
        __syncthreads();
    }
    if (threadIdx.x == 0) mx[p] = red[0] * (1.0f / 1728.0f);
}

// fp8 patch matrix, K-MAJOR: bmk[octet 0..215][pat 0..255][8B] — B staging becomes
// fully-coalesced 1KB gload16 chunks and B-LDS frag reads become stride-8B (2-way, free).
__global__ void k_bmat8(const float* __restrict__ x, uchar_t* __restrict__ bmk) {
    int p = blockIdx.x; int pr = p >> 4, pc = p & 15;
    for (int e = threadIdx.x; e < CH * KS * KS; e += 256) {
        int c = e / (KS * KS), rem = e % (KS * KS), i = rem / KS, j = rem % KS;
        bmk[(e >> 3) * (NP * 8) + p * 8 + (e & 7)] =
            f2e4m3(x[(c * XH + pr * KS + i) * XW + pc * KS + j]);
    }
}

// 4 column-shifted fp8 copies: y4[S][c][r][t] = fp8(ydec[c][r][t+S]), S in 0..3, 0-pad OOB.
__global__ void k_y4(const float* __restrict__ yd, uchar_t* __restrict__ y4) {
    int idx = blockIdx.x * 256 + threadIdx.x;
    if (idx >= 4 * 3 * HH * (WW / 4)) return;
    int q = idx % (WW / 4); int rem = idx / (WW / 4);
    int r = rem % HH; rem /= HH;
    int c = rem % 3; int S = rem / 3;
    const float* src = yd + (c * HH + r) * WW;
    union { uchar_t u[4]; unsigned v; } o;
    #pragma unroll
    for (int qq = 0; qq < 4; qq++) {
        int t = q * 4 + qq + S;
        o.u[qq] = f2e4m3(t < WW ? src[t] : 0.f);
    }
    ((unsigned*)(y4 + ((size_t)(S * 3 + c) * HH + r) * WW))[q] = o.v;
}

// -------------------- main MFMA correlation kernel (fp8) --------------------
// 256 thr (4 waves); XCD-banded flat grid: xcd = blk%8 owns a contiguous by-band so its
// ~2 MB working set (y4 band + bmk + maps) stays L2-resident -> A-DMA at L2 latency.
// Tile = 128 pos (4x32) x 128 patches; wave tile 64x64 of mfma_f32_32x32x16_fp8_fp8.
// A LDS [oct][pos][8B], B LDS [oct][pat][8B]: both frag-read at stride 8B (2-way, free).

__global__ __launch_bounds__(256, 4) void k_corr(
    const uchar_t* __restrict__ y4, const uchar_t* __restrict__ bmk,
    const ushort_t* __restrict__ s1m, const ushort_t* __restrict__ ivm,
    const float* __restrict__ mx, ushort_t* __restrict__ ps16)
{
    // ---- XCD-band mapping (heuristic blk%8 -> XCD; wrong mapping only costs speed) ----
    const int xcd = blockIdx.x & 7;
    const int idx = blockIdx.x >> 3;
    const int bstart = (187 * xcd) >> 3;
    const int bcnt = ((187 * (xcd + 1)) >> 3) - bstart;
    const int local_by = idx / 48;
    if (local_by >= bcnt) return;                    // idle filler block (before any barrier)
    const int rem = idx - local_by * 48;
    const int z = rem / 24;                          // patch half
    const int bx = rem - z * 24;
    const int by = bstart + local_by;

    __shared__ __align__(16) uchar_t Ab[8 * 1024];   // 8KB [oct][pos 0..127][8B]
    __shared__ __align__(16) uchar_t Bb[8 * 1024];   // 8KB [oct][pat 0..127][8B]
    float* red = (float*)Ab;                         // epilogue-only alias (post-sync)

    const int tid = threadIdx.x;
    const int wave = tid >> 6, lane = tid & 63;
    const int r0 = by * BROWS, w0 = bx * BCOLS;
    const int zbase = z * 128;

    // ---- A staging: round u: dest byte = u*1024 + 4*tid -> pos = tid>>1, half = tid&1 ----
    const int apos = tid >> 1, ahalf = tid & 1;
    const int aprow = apos >> 5, apcol = apos & 31;
    const int Sp = apcol & 3;                        // col mod 4 -> shifted copy (4B align)
    const int a_toff = Sp * (3 * HH * WW) + aprow * WW + (apcol - Sp) + ahalf * 4;
    uchar_t* adst = Ab + wave * 256;                 // + u*1024 (wave-uniform; +lane*4 by HW)

    // ---- B staging: wave w stages planes w and w+4; 1KB contiguous per plane ----
    const uchar_t* gb = bmk + zbase * 8 + lane * 16; // per-lane global (coalesced)
    uchar_t* bdst0 = Bb + wave * 1024;
    uchar_t* bdst1 = Bb + (wave + 4) * 1024;

    const int l31 = lane & 31, h = lane >> 5;
    const int wm = wave >> 1, wn = wave & 1;

    v16f acc[2][2];
    #pragma unroll
    for (int a = 0; a < 2; a++)
        #pragma unroll
        for (int b = 0; b < 2; b++)
            #pragma unroll
            for (int r = 0; r < 16; r++) acc[a][b][r] = 0.f;

    const uchar_t* abase = y4 + (size_t)r0 * WW + w0;    // octet cursor (c=0,i=0,j=0)
    int jc = 0, ic = 0;                                  // uniform cursor (SALU)

    #pragma unroll 1
    for (int s = 0; s < NSTEP; s++) {
        __syncthreads();                                 // old tile fully consumed
        #pragma unroll
        for (int u = 0; u < 8; u++) {                    // A octets (8 x 1KB)
            gload4(abase + a_toff, adst + u * 1024);
            abase += 8;
            if (++jc == 3) {
                jc = 0; abase += WW - 24;
                if (++ic == 24) { ic = 0; abase += (size_t)(HH - 24) * WW; }
            }
        }
        gload16(gb + (size_t)(s * 8 + wave) * (NP * 8),     bdst0);   // B plane w
        gload16(gb + (size_t)(s * 8 + wave + 4) * (NP * 8), bdst1);   // B plane w+4
        __syncthreads();                                 // staging landed

        ll_t af[2][4], bf[2][4];
        #pragma unroll
        for (int mt = 0; mt < 2; mt++)
            #pragma unroll
            for (int ks = 0; ks < 4; ks++)
                af[mt][ks] = *(const ll_t*)(Ab + (ks * 2 + h) * 1024 + (wm * 64 + mt * 32 + l31) * 8);
        #pragma unroll
        for (int nt = 0; nt < 2; nt++)
            #pragma unroll
            for (int ks = 0; ks < 4; ks++)
                bf[nt][ks] = *(const ll_t*)(Bb + (ks * 2 + h) * 1024 + (wn * 64 + nt * 32 + l31) * 8);
        #pragma unroll
        for (int ks = 0; ks < 4; ks++)
            #pragma unroll
            for (int mt = 0; mt < 2; mt++)
                #pragma unroll
                for (int nt = 0; nt < 2; nt++)
                    acc[mt][nt] = __builtin_amdgcn_mfma_f32_32x32x16_fp8_fp8(
                        af[mt][ks], bf[nt][ks], acc[mt][nt], 0, 0, 0);
    }

    // epilogue: approx score + per-(patch, block) max
    float mx0 = mx[zbase + wn * 64 + l31];
    float mx1 = mx[zbase + wn * 64 + 32 + l31];
    float best0 = -1e30f, best1 = -1e30f;
    #pragma unroll
    for (int mt = 0; mt < 2; mt++) {
        #pragma unroll
        for (int r = 0; r < 16; r++) {
            int row32 = (r & 3) + 8 * (r >> 2) + 4 * h;   // 32x32 C/D row (m74/m101)
            int posid = wm * 64 + mt * 32 + row32;
            int rg = r0 + (posid >> 5), wg = w0 + (posid & 31);
            bool valid = (rg < HC) && (wg < WC);
            int pos = rg * WC + wg;
            float S1 = valid ? bf2f(s1m[pos]) : 0.f;
            float iv = valid ? bf2f(ivm[pos]) : 0.f;
            float sc0 = valid ? (acc[mt][0][r] - mx0 * S1) * iv : -1e30f;
            float sc1 = valid ? (acc[mt][1][r] - mx1 * S1) * iv : -1e30f;
            best0 = fmaxf(best0, sc0);
            best1 = fmaxf(best1, sc1);
        }
    }
    best0 = fmaxf(best0, __shfl_xor(best0, 32));         // reduce over h
    best1 = fmaxf(best1, __shfl_xor(best1, 32));
    __syncthreads();                                     // full drain; Ab reused as red
    if (h == 0) {
        red[(wn * 64 + l31) * 2 + wm]      = best0;
        red[(wn * 64 + 32 + l31) * 2 + wm] = best1;
    }
    __syncthreads();
    if (tid < 128)
        ps16[(by * NBX + bx) * NP + zbase + tid] = f2bf(fmaxf(red[tid * 2], red[tid * 2 + 1]));
}

// -------------------- per-patch top-8 blocks --------------------

__global__ void k_select(const ushort_t* __restrict__ ps16, int* __restrict__ cand) {
    int p = blockIdx.x, tid = threadIdx.x;
    __shared__ float ls[NBLK];
    __shared__ float rs[256];
    __shared__ int   ri[256];
    for (int e = tid; e < NBLK; e += 256) ls[e] = bf2f(ps16[e * NP + p]);
    __syncthreads();
    for (int round = 0; round < NCAND; round++) {
        float bs = -1e38f; int bi = 0;
        for (int e = tid; e < NBLK; e += 256) if (ls[e] > bs) { bs = ls[e]; bi = e; }
        rs[tid] = bs; ri[tid] = bi; __syncthreads();
        for (int st = 128; st > 0; st >>= 1) {
            if (tid < st && rs[tid + st] > rs[tid]) { rs[tid] = rs[tid + st]; ri[tid] = ri[tid + st]; }
            __syncthreads();
        }
        int win = ri[0];
        if (tid == 0) cand[p * NCAND + round] = win;
        if (tid == (win & 255)) ls[win] = -1e38f;
        __syncthreads();
    }
}

// -------------------- exact fp32 rescore (recomputes window sums) + gather --------------------

__global__ void k_rescore(const int* __restrict__ cand, const float* __restrict__ xdec,
                          const float* __restrict__ ydec, const float* __restrict__ mx,
                          const float* __restrict__ yfull, float* __restrict__ out) {
    int p = blockIdx.x, tid = threadIdx.x;
    int pr = p >> 4, pc = p & 15;
    float mxp = mx[p];
    float best = -1e30f; int bpos = 0x7FFFFFFF;
    #pragma unroll 1
    for (int cdp = 0; cdp < 4; cdp++) {
        int cd = cdp * 2 + (tid >> 7);
        int blk = cand[p * NCAND + cd];
        int r0 = (blk / NBX) * BROWS, w0 = (blk % NBX) * BCOLS;
        int pi = tid & 127;
        int rg = r0 + (pi >> 5), wg = w0 + (pi & 31);
        if (rg < HC && wg < WC) {
            float sxy = 0.f, sy = 0.f, sy2 = 0.f;
            for (int c = 0; c < CH; c++) {
                #pragma unroll 1
                for (int i = 0; i < KS; i++) {
                    const float* yr = ydec + (c * HH + rg + i) * WW + wg;
                    const float* xr = xdec + (c * XH + pr * KS + i) * XW + pc * KS;
                    #pragma unroll
                    for (int j = 0; j < KS; j++) {
                        float yv = yr[j];
                        sxy = fmaf(yv, xr[j], sxy);
                        sy += yv;
                        sy2 = fmaf(yv, yv, sy2);
                    }
                }
            }
            float d2 = sy2 - sy * sy * (1.0f / 576.0f);
            int pos = rg * WC + wg;
            float sc = (sxy - mxp * sy) * rsqrtf(fmaxf(d2, 1e-20f));
            if (sc > best || (sc == best && pos < bpos)) { best = sc; bpos = pos; }
        }
    }
    __shared__ float rs[256];
    __shared__ int   ri[256];
    rs[tid] = best; ri[tid] = bpos; __syncthreads();
    for (int st = 128; st > 0; st >>= 1) {
        if (tid < st) {
            if (rs[tid + st] > rs[tid] || (rs[tid + st] == rs[tid] && ri[tid + st] < ri[tid])) {
                rs[tid] = rs[tid + st]; ri[tid] = ri[tid + st];
            }
        }
        __syncthreads();
    }
    int bestpos = ri[0];
    int row = bestpos / WC, col = bestpos % WC;
    for (int e = tid; e < CH * KS * KS; e += 256) {
        int c = e / (KS * KS), rem = e % (KS * KS), i = rem / KS, j = rem % KS;
        out[p * CH * KS * KS + e] = yfull[(c * HH + row + i) * WW + col + j];
    }
}

// -------------------- launch --------------------
// ws footprint unchanged from the passing R9: 11.5 MB writes, <12 MB transient reads.

extern "C" void kernel_launch(void* const* d_in, const int* in_sizes, int n_in,
                              void* d_out, int out_size, void* d_ws, size_t ws_size,
                              hipStream_t stream) {
    const float* xdec = (const float*)d_in[0];   // (1,3,384,384)
    const float* ydec = (const float*)d_in[1];   // (1,3,768,768)
    const float* y    = (const float*)d_in[2];   // (1,3,768,768)
    float* out = (float*)d_out;                  // (256,3,24,24)

    float* ws = (float*)d_ws;
    ushort_t* s1m16 = (ushort_t*)(ws + 0);         // 555025 u16
    ushort_t* ivm16 = (ushort_t*)(ws + 277520);    // 555025 u16
    float*    mx    = ws + 555040;                 // 256
    uchar_t*  Bmk   = (uchar_t*)(ws + 555296);     // 442368 B, k-major (16B-aligned)
    int*      cand  = (int*)(ws + 665888);         // 2048
    ushort_t* ps16  = (ushort_t*)(ws + 667936);    // 1,148,928 u16 [blk][pat]
    uchar_t*  y4    = (uchar_t*)(ws + 1242400);    // 7,077,888 B (16B-aligned)
    // box-sum temps alias ps16+y4 region (dead before k_y4/k_corr):
    float* ksum  = ws + 667936;                    // 589824
    float* ksum2 = ws + 1257760;                   // 589824
    float* h1    = ws + 1847584;                   // 572160
    float* h2    = ws + 2419744;                   // 572160 (end 2,991,904 < 3,011,872)

    k_colsum<<<(HH * WW + 255) / 256, 256, 0, stream>>>(ydec, ksum, ksum2);
    k_hsum<<<(HH * WC + 255) / 256, 256, 0, stream>>>(ksum, ksum2, h1, h2);
    k_vsum<<<(HC * WC + 255) / 256, 256, 0, stream>>>(h1, h2, s1m16, ivm16);
    k_meanx<<<NP, 256, 0, stream>>>(xdec, mx);
    k_bmat8<<<NP, 256, 0, stream>>>(xdec, Bmk);
    k_y4<<<(4 * 3 * HH * (WW / 4) + 255) / 256, 256, 0, stream>>>(ydec, y4);

    k_corr<<<NGRID, 256, 0, stream>>>(y4, Bmk, s1m16, ivm16, mx, ps16);
    k_select<<<NP, 256, 0, stream>>>(ps16, cand);
    k_rescore<<<NP, 256, 0, stream>>>(cand, xdec, ydec, mx, y, out);
}